// Round 10
// baseline (349.180 us; speedup 1.0000x reference)
//
#include <hip/hip_runtime.h>
#include <hip/hip_bf16.h>

#define NN 10000
#define NE 160000

#define SK_NORM   0.039528470752104741f   // 1/sqrt(640)
#define UP_NORM   0.125f                  // 1/8
#define M1_NORM   0.35355339059327373f    // 1/sqrt(8)
#define INV3      0.5773502691896258f
#define LIN_NORM  0.0027621358640099516f  // 1/sqrt(128)/32

__device__ __forceinline__ float siluf(float x) { return x / (1.0f + __expf(-x)); }

__device__ __forceinline__ unsigned short f2bf_bits(float x) {
    union { __hip_bfloat16 h; unsigned short u; } cv;
    cv.h = __float2bfloat16(x);
    return cv.u;
}
__device__ __forceinline__ float bflo(unsigned int w) { return __uint_as_float(w << 16); }
__device__ __forceinline__ float bfhi(unsigned int w) { return __uint_as_float(w & 0xffff0000u); }

typedef short bf16x8 __attribute__((ext_vector_type(8)));
typedef float f32x4  __attribute__((ext_vector_type(4)));

// a-frag scale: multiply 8 bf16 by f32 scalar, repack bf16
__device__ __forceinline__ bf16x8 scale8(bf16x8 f, float s) {
    union { bf16x8 v; unsigned int u[4]; } in, out;
    in.v = f;
    #pragma unroll
    for (int q = 0; q < 4; q++) {
        float lo = bflo(in.u[q]) * s;
        float hi = bfhi(in.u[q]) * s;
        out.u[q] = (unsigned int)f2bf_bits(lo) | ((unsigned int)f2bf_bits(hi) << 16);
    }
    return out.v;
}

// ---------------- K0a: detect edge_index dtype (int64 vs int32).
__global__ __launch_bounds__(256) void k_detect(const int* __restrict__ ei32, int* __restrict__ flag) {
    __shared__ int cnt;
    if (threadIdx.x == 0) cnt = 0;
    __syncthreads();
    int z = 0;
    for (int i = threadIdx.x; i < 1024; i += 256)
        if (ei32[2 * i + 1] == 0) z++;
    atomicAdd(&cnt, z);
    __syncthreads();
    if (threadIdx.x == 0) flag[0] = (cnt >= 512) ? 1 : 0;
}

// ---------------- K0b: extract sender/receiver as int32 regardless of source dtype
__global__ __launch_bounds__(256) void k_cvt(const int* __restrict__ ei32, const int* __restrict__ flag,
                                             int* __restrict__ snd, int* __restrict__ rcv) {
    int e = blockIdx.x * 256 + threadIdx.x;
    if (e >= NE) return;
    if (flag[0]) {
        const long long* e64 = (const long long*)ei32;
        snd[e] = (int)e64[e];
        rcv[e] = (int)e64[NE + e];
    } else {
        snd[e] = ei32[e];
        rcv[e] = ei32[NE + e];
    }
}

// ---------------- K_wprep: bf16-transpose weight panels for k_node
__global__ __launch_bounds__(256) void k_wprep(
    const float* __restrict__ Wsk_s, const float* __restrict__ Wsk_v,
    const float* __restrict__ Wu0, const float* __restrict__ Wu1,
    unsigned short* __restrict__ WsT, unsigned short* __restrict__ WvT,
    unsigned short* __restrict__ Wu0T, unsigned short* __restrict__ Wu1T) {
    int idx = blockIdx.x * 256 + threadIdx.x;
    if (idx < 128 * 640) {
        int v = idx / 640, k = idx - v * 640;
        int a = k >> 6, u = k & 63;
        WsT[idx] = f2bf_bits(Wsk_s[(u * 10 + a) * 128 + v]);
        return;
    }
    int i2 = idx - 128 * 640;
    if (i2 < 64 * 640) {
        int v = i2 / 640, k = i2 - v * 640;
        int a = k >> 6, u = k & 63;
        WvT[i2] = f2bf_bits(Wsk_v[(u * 10 + a) * 64 + v]);
        return;
    }
    int i3 = i2 - 64 * 640;
    if (i3 < 4096) { Wu0T[i3] = f2bf_bits(Wu0[(i3 & 63) * 64 + (i3 >> 6)]); return; }
    int i4 = i3 - 4096;
    if (i4 < 4096) { Wu1T[i4] = f2bf_bits(Wu1[(i4 & 63) * 64 + (i4 >> 6)]); }
}

// ---------------- K_wprep2: bf16-transpose edge-MLP weights -> [n][k] global panels
// M1T: 64 x 32 (k<8 real, rest 0); M2T/M3T: 64 x 64; M4T: 256 x 64.
__global__ __launch_bounds__(256) void k_wprep2(
    const float* __restrict__ M1, const float* __restrict__ M2,
    const float* __restrict__ M3, const float* __restrict__ M4,
    unsigned short* __restrict__ M1T, unsigned short* __restrict__ M2T,
    unsigned short* __restrict__ M3T, unsigned short* __restrict__ M4T) {
    int idx = blockIdx.x * 256 + threadIdx.x;
    if (idx < 64 * 32) {
        int n = idx >> 5, k = idx & 31;
        M1T[idx] = (k < 8) ? f2bf_bits(M1[k * 64 + n]) : (unsigned short)0;
        return;
    }
    int i2 = idx - 64 * 32;
    if (i2 < 64 * 64) {
        int n = i2 >> 6, k = i2 & 63;
        M2T[i2] = f2bf_bits(M2[k * 64 + n]);
        M3T[i2] = f2bf_bits(M3[k * 64 + n]);
        return;
    }
    int i3 = i2 - 64 * 64;
    if (i3 < 256 * 64) {
        int n = i3 >> 6, k = i3 & 63;
        M4T[i3] = f2bf_bits(M4[k * 256 + n]);
    }
}

// ---------------- K_node: fused MFMA node-side einsums (16 nodes/block).
#define FEAT_STRIDE 72

__global__ __launch_bounds__(256) void k_node(
    const float* __restrict__ node_attrs, const float* __restrict__ node_feats,
    const unsigned short* __restrict__ WsT, const unsigned short* __restrict__ WvT,
    const unsigned short* __restrict__ Wu0T, const unsigned short* __restrict__ Wu1T,
    float* __restrict__ sc_s, float* __restrict__ sc_v,
    float* __restrict__ x0u, float* __restrict__ x1u) {
    __shared__ unsigned short feat[4 * 16 * FEAT_STRIDE];  // plane 0=x0, 1..3=x1_i
    __shared__ float attrs_l[16 * 12];
    __shared__ float x1st[16 * 64 * 4];                    // packed float4 staging

    int t = threadIdx.x;
    int nbase = blockIdx.x * 16;

    {
        int node = t >> 4, seg = t & 15;
        const float* src = node_feats + (long)(nbase + node) * 256 + seg * 16;
        #pragma unroll
        for (int f = 0; f < 16; f += 4) {
            float4 v4 = *(const float4*)(src + f);
            float vv[4] = {v4.x, v4.y, v4.z, v4.w};
            #pragma unroll
            for (int j = 0; j < 4; j++) {
                int fi = seg * 16 + f + j;
                unsigned short b = f2bf_bits(vv[j]);
                if (fi < 64) {
                    feat[(0 * 16 + node) * FEAT_STRIDE + fi] = b;
                } else {
                    int r = fi - 64;
                    int u = r / 3;
                    int i = r - u * 3;
                    feat[((1 + i) * 16 + node) * FEAT_STRIDE + u] = b;
                }
            }
        }
    }
    if (t < 160) {
        int node = t / 10, a = t - node * 10;
        attrs_l[node * 12 + a] = node_attrs[(long)(nbase + node) * 10 + a];
    }
    __syncthreads();

    int wv = t >> 6;
    int lane = t & 63;
    int lo = lane & 15;
    int quad = lane >> 4;
    const f32x4 zacc = {0.f, 0.f, 0.f, 0.f};

    float af[10];
    #pragma unroll
    for (int a = 0; a < 10; a++) af[a] = attrs_l[lo * 12 + a];
    bf16x8 ff0h0 = *(const bf16x8*)&feat[(0 * 16 + lo) * FEAT_STRIDE + 0 * 32 + quad * 8];
    bf16x8 ff0h1 = *(const bf16x8*)&feat[(0 * 16 + lo) * FEAT_STRIDE + 1 * 32 + quad * 8];
    bf16x8 ff1h0 = *(const bf16x8*)&feat[(1 * 16 + lo) * FEAT_STRIDE + 0 * 32 + quad * 8];
    bf16x8 ff1h1 = *(const bf16x8*)&feat[(1 * 16 + lo) * FEAT_STRIDE + 1 * 32 + quad * 8];
    bf16x8 ff2h0 = *(const bf16x8*)&feat[(2 * 16 + lo) * FEAT_STRIDE + 0 * 32 + quad * 8];
    bf16x8 ff2h1 = *(const bf16x8*)&feat[(2 * 16 + lo) * FEAT_STRIDE + 1 * 32 + quad * 8];
    bf16x8 ff3h0 = *(const bf16x8*)&feat[(3 * 16 + lo) * FEAT_STRIDE + 0 * 32 + quad * 8];
    bf16x8 ff3h1 = *(const bf16x8*)&feat[(3 * 16 + lo) * FEAT_STRIDE + 1 * 32 + quad * 8];

    #pragma unroll 1
    for (int q = 0; q < 9; q++) {
        int tau = wv + q * 4;
        int kind, vt, iidx = 0, plane;
        const unsigned short* brow;
        if (tau < 8)       { kind = 0; vt = tau;               plane = 0;        brow = WsT  + (size_t)(vt * 16 + lo) * 640; }
        else if (tau < 20) { kind = 1; iidx = (tau - 8) >> 2;  vt = (tau - 8) & 3;  plane = 1 + iidx; brow = WvT  + (size_t)(vt * 16 + lo) * 640; }
        else if (tau < 24) { kind = 2; vt = tau - 20;          plane = 0;        brow = Wu0T + (size_t)(vt * 16 + lo) * 64; }
        else               { kind = 3; iidx = (tau - 24) >> 2; vt = (tau - 24) & 3; plane = 1 + iidx; brow = Wu1T + (size_t)(vt * 16 + lo) * 64; }

        bf16x8 fa0, fa1;
        if (plane == 0)      { fa0 = ff0h0; fa1 = ff0h1; }
        else if (plane == 1) { fa0 = ff1h0; fa1 = ff1h1; }
        else if (plane == 2) { fa0 = ff2h0; fa1 = ff2h1; }
        else                 { fa0 = ff3h0; fa1 = ff3h1; }

        f32x4 acc = zacc;
        if (kind <= 1) {
            #pragma unroll
            for (int kc = 0; kc < 20; kc++) {
                bf16x8 b = *(const bf16x8*)(brow + kc * 32 + quad * 8);
                bf16x8 a = scale8((kc & 1) ? fa1 : fa0, af[kc >> 1]);
                acc = __builtin_amdgcn_mfma_f32_16x16x32_bf16(a, b, acc, 0, 0, 0);
            }
        } else {
            bf16x8 b0 = *(const bf16x8*)(brow + quad * 8);
            bf16x8 b1 = *(const bf16x8*)(brow + 32 + quad * 8);
            acc = __builtin_amdgcn_mfma_f32_16x16x32_bf16(fa0, b0, acc, 0, 0, 0);
            acc = __builtin_amdgcn_mfma_f32_16x16x32_bf16(fa1, b1, acc, 0, 0, 0);
        }

        #pragma unroll
        for (int r = 0; r < 4; r++) {
            int nrow = nbase + quad * 4 + r;
            float cv = acc[r];
            if (kind == 0)      sc_s[(long)nrow * 128 + vt * 16 + lo] = cv * SK_NORM;
            else if (kind == 1) sc_v[(long)nrow * 192 + iidx * 64 + vt * 16 + lo] = cv * SK_NORM;
            else if (kind == 2) x0u[(long)nrow * 64 + vt * 16 + lo] = cv * UP_NORM;
            else                x1st[((quad * 4 + r) * 64 + vt * 16 + lo) * 4 + iidx] = cv * UP_NORM;
        }
    }
    __syncthreads();
    #pragma unroll
    for (int j = 0; j < 4; j++) {
        int idx = t + j * 256;
        int node = idx >> 6, v = idx & 63;
        ((float4*)x1u)[(long)(nbase + node) * 64 + v] = *(const float4*)&x1st[idx * 4];
    }
}

// ---------------- K3: CSR build by receiver (epk = packed {sender, edge})
__global__ __launch_bounds__(256) void k_hist(const int* __restrict__ rcv, int* __restrict__ counts) {
    int e = blockIdx.x * 256 + threadIdx.x;
    if (e < NE) atomicAdd(&counts[rcv[e]], 1);
}

__global__ __launch_bounds__(1024) void k_scan(const int* __restrict__ counts, int* __restrict__ offsets) {
    __shared__ int partial[1024];
    int t = threadIdx.x;
    const int CHUNK = (NN + 1023) / 1024;   // 10
    int base = t * CHUNK;
    int s = 0;
    for (int i = 0; i < CHUNK; i++) if (base + i < NN) s += counts[base + i];
    partial[t] = s;
    __syncthreads();
    for (int d = 1; d < 1024; d *= 2) {
        int v = (t >= d) ? partial[t - d] : 0;
        __syncthreads();
        partial[t] += v;
        __syncthreads();
    }
    int excl = (t == 0) ? 0 : partial[t - 1];
    for (int i = 0; i < CHUNK; i++) {
        if (base + i < NN) { offsets[base + i] = excl; excl += counts[base + i]; }
    }
    if (t == 1023) offsets[NN] = partial[1023];
}

__global__ __launch_bounds__(256) void k_fill(const int* __restrict__ rcv, const int* __restrict__ snd,
                                              const int* __restrict__ offsets,
                                              int* __restrict__ cursor, int2* __restrict__ epk) {
    int e = blockIdx.x * 256 + threadIdx.x;
    if (e < NE) {
        int r = rcv[e];
        int pos = atomicAdd(&cursor[r], 1);
        epk[offsets[r] + pos] = make_int2(snd[e], e);
    }
}

// ---------------- K_eprep: CSR-ordered edge streams: sndp[j], earp[j], eaip[j]
__global__ __launch_bounds__(256) void k_eprep(const int2* __restrict__ epk,
                                               const float4* __restrict__ ear, const float4* __restrict__ eai,
                                               int* __restrict__ sndp,
                                               float4* __restrict__ earp, float4* __restrict__ eaip) {
    int j = blockIdx.x * 256 + threadIdx.x;
    if (j >= NE) return;
    int2 se = epk[j];
    sndp[j] = se.x;
    earp[j] = ear[se.y];
    eaip[j] = eai[se.y];
}

// ---------------- K2: edge MLP via MFMA, CSR-slot order -> twp (bf16, NE x 256)
// B-fragments read DIRECTLY from global pre-transposed bf16 panels (L2-resident,
// no intra-wave B reuse => LDS staging buys nothing). No weight LDS, no barriers
// (hid/obuf are per-wave tiles; same-wave LDS RAW ordered by compiler lgkmcnt).
#define HID_STRIDE 72
#define OB_STRIDE  40

__global__ __launch_bounds__(256) void k_edge_mlp(
    const int2* __restrict__ epk, const float* __restrict__ edge_feats,
    const unsigned short* __restrict__ M1T, const unsigned short* __restrict__ M2T,
    const unsigned short* __restrict__ M3T, const unsigned short* __restrict__ M4T,
    __hip_bfloat16* __restrict__ twp) {
    __shared__ unsigned short hid[4][16 * HID_STRIDE];
    __shared__ unsigned short obuf[4][16 * OB_STRIDE];

    int t = threadIdx.x;
    int wv = t >> 6;
    int lane = t & 63;
    int lo = lane & 15;
    int quad = lane >> 4;
    int jbase = blockIdx.x * 64 + wv * 16;
    unsigned short* myhid = hid[wv];
    unsigned short* myob  = obuf[wv];
    const f32x4 zacc = {0.f, 0.f, 0.f, 0.f};

    // ---- layer 1: [16x8] @ [8x64] (K padded to 32), silu ----
    bf16x8 a1 = {0, 0, 0, 0, 0, 0, 0, 0};
    if (quad == 0) {
        int e = epk[jbase + lo].y;          // gather source edge id
        const float4* ef = (const float4*)(edge_feats + (long)e * 8);
        float4 f0 = ef[0];
        float4 f1 = ef[1];
        union { unsigned short us[8]; bf16x8 v; } pk;
        pk.us[0] = f2bf_bits(f0.x * M1_NORM); pk.us[1] = f2bf_bits(f0.y * M1_NORM);
        pk.us[2] = f2bf_bits(f0.z * M1_NORM); pk.us[3] = f2bf_bits(f0.w * M1_NORM);
        pk.us[4] = f2bf_bits(f1.x * M1_NORM); pk.us[5] = f2bf_bits(f1.y * M1_NORM);
        pk.us[6] = f2bf_bits(f1.z * M1_NORM); pk.us[7] = f2bf_bits(f1.w * M1_NORM);
        a1 = pk.v;
    }
    {
        f32x4 acc[4];
        #pragma unroll
        for (int nt = 0; nt < 4; nt++) {
            bf16x8 b = *(const bf16x8*)(M1T + (size_t)(nt * 16 + lo) * 32 + quad * 8);
            acc[nt] = __builtin_amdgcn_mfma_f32_16x16x32_bf16(a1, b, zacc, 0, 0, 0);
        }
        #pragma unroll
        for (int nt = 0; nt < 4; nt++)
            #pragma unroll
            for (int r = 0; r < 4; r++)
                myhid[(quad * 4 + r) * HID_STRIDE + nt * 16 + lo] = f2bf_bits(siluf(acc[nt][r]));
    }

    // ---- layers 2,3: [16x64] @ [64x64] /8, silu ----
    const unsigned short* wts[2] = {M2T, M3T};
    #pragma unroll
    for (int L = 0; L < 2; L++) {
        const unsigned short* wt = wts[L];
        bf16x8 a0 = *(const bf16x8*)&myhid[lo * HID_STRIDE + quad * 8];
        bf16x8 a1v = *(const bf16x8*)&myhid[lo * HID_STRIDE + 32 + quad * 8];
        f32x4 acc[4];
        #pragma unroll
        for (int nt = 0; nt < 4; nt++) {
            bf16x8 b0 = *(const bf16x8*)(wt + (size_t)(nt * 16 + lo) * 64 + quad * 8);
            bf16x8 b1 = *(const bf16x8*)(wt + (size_t)(nt * 16 + lo) * 64 + 32 + quad * 8);
            acc[nt] = __builtin_amdgcn_mfma_f32_16x16x32_bf16(a0, b0, zacc, 0, 0, 0);
            acc[nt] = __builtin_amdgcn_mfma_f32_16x16x32_bf16(a1v, b1, acc[nt], 0, 0, 0);
        }
        #pragma unroll
        for (int nt = 0; nt < 4; nt++)
            #pragma unroll
            for (int r = 0; r < 4; r++)
                myhid[(quad * 4 + r) * HID_STRIDE + nt * 16 + lo] = f2bf_bits(siluf(acc[nt][r] * 0.125f));
    }

    // ---- layer 4: [16x64] @ [64x256] /8, interleaved (A,B)/(C,D) pair output ----
    {
        bf16x8 a0 = *(const bf16x8*)&myhid[lo * HID_STRIDE + quad * 8];
        bf16x8 a1v = *(const bf16x8*)&myhid[lo * HID_STRIDE + 32 + quad * 8];
        int sedge = lane >> 2, sch = lane & 3;
        #pragma unroll 1
        for (int rd = 0; rd < 8; rd++) {
            f32x4 acc2[2];
            #pragma unroll
            for (int p = 0; p < 2; p++) {
                int n = (rd < 4) ? (p * 64 + rd * 16 + lo) : (128 + p * 64 + (rd - 4) * 16 + lo);
                bf16x8 b0 = *(const bf16x8*)(M4T + (size_t)n * 64 + quad * 8);
                bf16x8 b1 = *(const bf16x8*)(M4T + (size_t)n * 64 + 32 + quad * 8);
                acc2[p] = __builtin_amdgcn_mfma_f32_16x16x32_bf16(a0, b0, zacc, 0, 0, 0);
                acc2[p] = __builtin_amdgcn_mfma_f32_16x16x32_bf16(a1v, b1, acc2[p], 0, 0, 0);
            }
            #pragma unroll
            for (int p = 0; p < 2; p++)
                #pragma unroll
                for (int r = 0; r < 4; r++)
                    myob[(quad * 4 + r) * OB_STRIDE + 2 * lo + p] = f2bf_bits(acc2[p][r] * 0.125f);
            bf16x8 vv = *(const bf16x8*)&myob[sedge * OB_STRIDE + sch * 8];
            *(bf16x8*)(twp + (long)(jbase + sedge) * 256 + rd * 32 + sch * 8) = vv;
        }
    }
}

// ---------------- K4: conv_tp + segment sum -> msg (bf16, NN x 1024)
#define CB 8
__global__ __launch_bounds__(256) void k_conv(
    const int* __restrict__ offsets, const int* __restrict__ sndp,
    const float4* __restrict__ earp, const float4* __restrict__ eaip,
    const float* __restrict__ x0u, const float* __restrict__ x1u,
    const __hip_bfloat16* __restrict__ twp,
    unsigned short* __restrict__ msgbuf) {
    int n = blockIdx.x;
    int t = threadIdx.x;
    int u = t & 127;
    int ri = t >> 7;
    int beg = offsets[n], end = offsets[n + 1];
    const float4* ea4 = ri ? eaip : earp;
    float a0 = 0.f, a1 = 0.f, a2 = 0.f, a3 = 0.f;
    if (u < 64) {
        const int tsel = 2 * u;
        for (int jb = beg; jb < end; jb += CB) {
            unsigned int twd[CB]; float x0v[CB]; float4 y[CB];
            #pragma unroll
            for (int p = 0; p < CB; p++) {
                int j = jb + p;
                int jc = (j < end) ? j : (end - 1);
                int s = sndp[jc];
                y[p] = ea4[jc];
                x0v[p] = x0u[(long)s * 64 + u];
                twd[p] = (j < end) ? *(const unsigned int*)(twp + (long)jc * 256 + tsel) : 0u;
            }
            #pragma unroll
            for (int p = 0; p < CB; p++) {
                float wA = bflo(twd[p]), wB = bfhi(twd[p]);
                a0 += x0v[p] * y[p].x * wA;
                float xb = x0v[p] * wB;
                a1 += xb * y[p].y; a2 += xb * y[p].z; a3 += xb * y[p].w;
            }
        }
    } else {
        int uu = u - 64;
        const int tsel = 128 + 2 * uu;
        for (int jb = beg; jb < end; jb += CB) {
            unsigned int twd[CB]; float4 x1v[CB]; float4 y[CB];
            #pragma unroll
            for (int p = 0; p < CB; p++) {
                int j = jb + p;
                int jc = (j < end) ? j : (end - 1);
                int s = sndp[jc];
                y[p] = ea4[jc];
                x1v[p] = ((const float4*)x1u)[(long)s * 64 + uu];
                twd[p] = (j < end) ? *(const unsigned int*)(twp + (long)jc * 256 + tsel) : 0u;
            }
            #pragma unroll
            for (int p = 0; p < CB; p++) {
                float wC = bflo(twd[p]), wD = bfhi(twd[p]);
                a0 += (x1v[p].x * y[p].y + x1v[p].y * y[p].z + x1v[p].z * y[p].w) * INV3 * wD;
                float yc = y[p].x * wC;
                a1 += x1v[p].x * yc; a2 += x1v[p].y * yc; a3 += x1v[p].z * yc;
            }
        }
    }
    unsigned short* mb = msgbuf + (long)n * 1024;
    mb[ri * 128 + u] = f2bf_bits(a0);
    int vb = 256 + ri * 384 + u;
    mb[vb + 0]   = f2bf_bits(a1);
    mb[vb + 128] = f2bf_bits(a2);
    mb[vb + 256] = f2bf_bits(a3);
}

// ---------------- K5: MFMA lin + skip + gate + output.
#define WL_STRIDE 136   // 128 k + 8 pad (16B-aligned rows)
#define SV_STRIDE 129   // sval row pad
#define VV_STRIDE 65    // vval row pad

__global__ __launch_bounds__(256) void k_lin(
    const unsigned short* __restrict__ msgbuf,
    const float* __restrict__ sc_s, const float* __restrict__ sc_v,
    const float* __restrict__ W_lin_s, const float* __restrict__ W_lin_v,
    float* __restrict__ out) {
    __shared__ unsigned short wst[128 * WL_STRIDE];
    __shared__ unsigned short wvt[64 * WL_STRIDE];
    __shared__ float sval[2 * 16 * SV_STRIDE];
    __shared__ float vval[2 * 3 * 16 * VV_STRIDE];

    int t = threadIdx.x;
    for (int idx = t; idx < 128 * 128; idx += 256) {
        int k = idx >> 7, v = idx & 127;
        wst[v * WL_STRIDE + k] = f2bf_bits(W_lin_s[idx]);
    }
    for (int idx = t; idx < 128 * 64; idx += 256) {
        int k = idx >> 6, v = idx & 63;
        wvt[v * WL_STRIDE + k] = f2bf_bits(W_lin_v[idx]);
    }
    __syncthreads();

    int wv = t >> 6;
    int lane = t & 63;
    int lo = lane & 15;
    int quad = lane >> 4;
    const f32x4 zacc = {0.f, 0.f, 0.f, 0.f};

    for (int g = blockIdx.x; g < NN / 16; g += gridDim.x) {
        long nbase = (long)g * 16;
        const unsigned short* arow = msgbuf + (nbase + lo) * 1024;

        #pragma unroll 1
        for (int q = 0; q < 10; q++) {
            int tau = wv + q * 4;
            int aoff, cidx, cstride;
            const unsigned short* bptr;
            float* cbuf;
            if (tau < 16) {
                int ri = tau >> 3, vt = tau & 7;
                aoff = ri * 128;
                bptr = &wst[(vt * 16 + lo) * WL_STRIDE];
                cbuf = sval;
                cidx = (ri * 16) * SV_STRIDE + vt * 16 + lo;
                cstride = SV_STRIDE;
            } else {
                int tp = tau - 16;
                int ri = tp / 12, rem = tp % 12;
                int i = rem >> 2, vt = rem & 3;
                aoff = 256 + ri * 384 + i * 128;
                bptr = &wvt[(vt * 16 + lo) * WL_STRIDE];
                cbuf = vval;
                cidx = ((ri * 3 + i) * 16) * VV_STRIDE + vt * 16 + lo;
                cstride = VV_STRIDE;
            }
            f32x4 acc = zacc;
            #pragma unroll
            for (int ks = 0; ks < 4; ks++) {
                bf16x8 a = *(const bf16x8*)(arow + aoff + ks * 32 + quad * 8);
                bf16x8 b = *(const bf16x8*)(bptr + ks * 32 + quad * 8);
                acc = __builtin_amdgcn_mfma_f32_16x16x32_bf16(a, b, acc, 0, 0, 0);
            }
            #pragma unroll
            for (int r = 0; r < 4; r++)
                cbuf[cidx + (quad * 4 + r) * cstride] = acc[r] * LIN_NORM;
        }
        __syncthreads();

        #pragma unroll 1
        for (int j = 0; j < 16; j++) {
            int c = t;
            long gn = nbase + j;
            float re, im;
            if (c < 64) {
                float sr = sval[(0 * 16 + j) * SV_STRIDE + c] + sc_s[gn * 128 + c];
                float si = sval[(1 * 16 + j) * SV_STRIDE + c];
                re = siluf(sr); im = siluf(si);
            } else {
                int rem = c - 64;
                int v = rem / 3;
                int i = rem - v * 3;
                float gr = siluf(sval[(0 * 16 + j) * SV_STRIDE + 64 + v] + sc_s[gn * 128 + 64 + v]);
                float gi = siluf(sval[(1 * 16 + j) * SV_STRIDE + 64 + v]);
                float lr = vval[((0 * 3 + i) * 16 + j) * VV_STRIDE + v] + sc_v[gn * 192 + i * 64 + v];
                float li = vval[((1 * 3 + i) * 16 + j) * VV_STRIDE + v];
                re = lr * gr; im = li * gi;
            }
            ((float2*)out)[gn * 256 + c] = make_float2(re, im);
        }
        __syncthreads();
    }
}

extern "C" void kernel_launch(void* const* d_in, const int* in_sizes, int n_in,
                              void* d_out, int out_size, void* d_ws, size_t ws_size,
                              hipStream_t stream) {
    const float* node_attrs = (const float*)d_in[0];
    const float* node_feats = (const float*)d_in[1];
    const float* ear        = (const float*)d_in[2];
    const float* eai        = (const float*)d_in[3];
    const float* edge_feats = (const float*)d_in[4];
    const float* W_up0      = (const float*)d_in[5];
    const float* W_up1      = (const float*)d_in[6];
    const float* M1         = (const float*)d_in[7];
    const float* M2         = (const float*)d_in[8];
    const float* M3         = (const float*)d_in[9];
    const float* M4         = (const float*)d_in[10];
    const float* W_lin_s    = (const float*)d_in[11];
    const float* W_lin_v    = (const float*)d_in[12];
    const float* W_sk_s     = (const float*)d_in[13];
    const float* W_sk_v     = (const float*)d_in[14];
    const int*   ei         = (const int*)d_in[15];

    char* ws = (char*)d_ws;
    size_t o_x0u = 0;
    size_t o_x1u = o_x0u + (size_t)NN * 64 * 4;
    size_t o_scs = o_x1u + (size_t)NN * 256 * 4;      // x1u4: [n][64][4]
    size_t o_scv = o_scs + (size_t)NN * 128 * 4;
    size_t o_tw  = o_scv + (size_t)NN * 192 * 4;
    size_t o_cnt = o_tw  + (size_t)NE * 256 * 2;
    size_t o_cur = o_cnt + (size_t)NN * 4;
    size_t o_ofs = o_cur + (size_t)NN * 4;
    size_t o_epk = o_ofs + (size_t)(NN + 1) * 4 + 60;   // pad to 16B
    size_t o_snd = o_epk + (size_t)NE * 8;
    size_t o_rcv = o_snd + (size_t)NE * 4;
    size_t o_flg = o_rcv + (size_t)NE * 4;
    size_t o_msg = o_flg + 64;
    size_t o_wst = o_msg + (size_t)NN * 1024 * 2;
    size_t o_wvt = o_wst + (size_t)128 * 640 * 2;
    size_t o_wu0 = o_wvt + (size_t)64 * 640 * 2;
    size_t o_wu1 = o_wu0 + (size_t)4096 * 2;
    size_t o_snp = o_wu1 + (size_t)4096 * 2;            // sndp (CSR order)
    size_t o_erp = o_snp + (size_t)NE * 4;
    size_t o_eip = o_erp + (size_t)NE * 16;
    size_t o_m1t = o_eip + (size_t)NE * 16;
    size_t o_m2t = o_m1t + (size_t)64 * 32 * 2;
    size_t o_m3t = o_m2t + (size_t)64 * 64 * 2;
    size_t o_m4t = o_m3t + (size_t)64 * 64 * 2;
    float* x0u = (float*)(ws + o_x0u);
    float* x1u = (float*)(ws + o_x1u);
    float* sc_s = (float*)(ws + o_scs);
    float* sc_v = (float*)(ws + o_scv);
    __hip_bfloat16* twp = (__hip_bfloat16*)(ws + o_tw);
    int* counts  = (int*)(ws + o_cnt);
    int* cursor  = (int*)(ws + o_cur);
    int* offsets = (int*)(ws + o_ofs);
    int2* epk    = (int2*)(ws + o_epk);
    int* snd     = (int*)(ws + o_snd);
    int* rcv     = (int*)(ws + o_rcv);
    int* flag    = (int*)(ws + o_flg);
    unsigned short* msgbuf = (unsigned short*)(ws + o_msg);
    unsigned short* WsT  = (unsigned short*)(ws + o_wst);
    unsigned short* WvT  = (unsigned short*)(ws + o_wvt);
    unsigned short* Wu0T = (unsigned short*)(ws + o_wu0);
    unsigned short* Wu1T = (unsigned short*)(ws + o_wu1);
    int*    sndp = (int*)(ws + o_snp);
    float4* earp = (float4*)(ws + o_erp);
    float4* eaip = (float4*)(ws + o_eip);
    unsigned short* M1T = (unsigned short*)(ws + o_m1t);
    unsigned short* M2T = (unsigned short*)(ws + o_m2t);
    unsigned short* M3T = (unsigned short*)(ws + o_m3t);
    unsigned short* M4T = (unsigned short*)(ws + o_m4t);

    hipMemsetAsync(ws + o_cnt, 0, (size_t)NN * 8, stream);

    dim3 b256(256), b1024(1024);
    k_detect<<<dim3(1), b256, 0, stream>>>(ei, flag);
    k_cvt   <<<dim3((NE + 255) / 256), b256, 0, stream>>>(ei, flag, snd, rcv);
    k_hist<<<dim3((NE + 255) / 256), b256, 0, stream>>>(rcv, counts);
    k_scan<<<dim3(1), b1024, 0, stream>>>(counts, offsets);
    k_fill<<<dim3((NE + 255) / 256), b256, 0, stream>>>(rcv, snd, offsets, cursor, epk);
    k_eprep<<<dim3((NE + 255) / 256), b256, 0, stream>>>(epk, (const float4*)ear, (const float4*)eai,
                                                         sndp, earp, eaip);
    k_wprep <<<dim3(512), b256, 0, stream>>>(W_sk_s, W_sk_v, W_up0, W_up1, WsT, WvT, Wu0T, Wu1T);
    k_wprep2<<<dim3(104), b256, 0, stream>>>(M1, M2, M3, M4, M1T, M2T, M3T, M4T);
    k_node  <<<dim3(NN / 16), b256, 0, stream>>>(node_attrs, node_feats, WsT, WvT, Wu0T, Wu1T,
                                                 sc_s, sc_v, x0u, x1u);
    k_edge_mlp<<<dim3(NE / 64), b256, 0, stream>>>(epk, edge_feats, M1T, M2T, M3T, M4T, twp);
    k_conv<<<dim3(NN), b256, 0, stream>>>(offsets, sndp, earp, eaip, x0u, x1u, twp, msgbuf);
    k_lin <<<dim3(224), b256, 0, stream>>>(msgbuf, sc_s, sc_v, W_lin_s, W_lin_v, (float*)d_out);
}

// Round 11
// 322.480 us; speedup vs baseline: 1.0828x; 1.0828x over previous
//
#include <hip/hip_runtime.h>
#include <hip/hip_bf16.h>

#define NN 10000
#define NE 160000

#define SK_NORM   0.039528470752104741f   // 1/sqrt(640)
#define UP_NORM   0.125f                  // 1/8
#define M1_NORM   0.35355339059327373f    // 1/sqrt(8)
#define INV3      0.5773502691896258f
#define LIN_NORM  0.0027621358640099516f  // 1/sqrt(128)/32

__device__ __forceinline__ float siluf(float x) { return x / (1.0f + __expf(-x)); }

__device__ __forceinline__ unsigned short f2bf_bits(float x) {
    union { __hip_bfloat16 h; unsigned short u; } cv;
    cv.h = __float2bfloat16(x);
    return cv.u;
}
__device__ __forceinline__ float bflo(unsigned int w) { return __uint_as_float(w << 16); }
__device__ __forceinline__ float bfhi(unsigned int w) { return __uint_as_float(w & 0xffff0000u); }

typedef short bf16x8 __attribute__((ext_vector_type(8)));
typedef float f32x4  __attribute__((ext_vector_type(4)));

// a-frag scale: multiply 8 bf16 by f32 scalar, repack bf16
__device__ __forceinline__ bf16x8 scale8(bf16x8 f, float s) {
    union { bf16x8 v; unsigned int u[4]; } in, out;
    in.v = f;
    #pragma unroll
    for (int q = 0; q < 4; q++) {
        float lo = bflo(in.u[q]) * s;
        float hi = bfhi(in.u[q]) * s;
        out.u[q] = (unsigned int)f2bf_bits(lo) | ((unsigned int)f2bf_bits(hi) << 16);
    }
    return out.v;
}

// ---------------- K0a: detect edge_index dtype (int64 vs int32).
__global__ __launch_bounds__(256) void k_detect(const int* __restrict__ ei32, int* __restrict__ flag) {
    __shared__ int cnt;
    if (threadIdx.x == 0) cnt = 0;
    __syncthreads();
    int z = 0;
    for (int i = threadIdx.x; i < 1024; i += 256)
        if (ei32[2 * i + 1] == 0) z++;
    atomicAdd(&cnt, z);
    __syncthreads();
    if (threadIdx.x == 0) flag[0] = (cnt >= 512) ? 1 : 0;
}

// ---------------- K0b: extract sender/receiver as int32 regardless of source dtype
__global__ __launch_bounds__(256) void k_cvt(const int* __restrict__ ei32, const int* __restrict__ flag,
                                             int* __restrict__ snd, int* __restrict__ rcv) {
    int e = blockIdx.x * 256 + threadIdx.x;
    if (e >= NE) return;
    if (flag[0]) {
        const long long* e64 = (const long long*)ei32;
        snd[e] = (int)e64[e];
        rcv[e] = (int)e64[NE + e];
    } else {
        snd[e] = ei32[e];
        rcv[e] = ei32[NE + e];
    }
}

// ---------------- K_wprep: bf16-transpose weight panels for k_node
__global__ __launch_bounds__(256) void k_wprep(
    const float* __restrict__ Wsk_s, const float* __restrict__ Wsk_v,
    const float* __restrict__ Wu0, const float* __restrict__ Wu1,
    unsigned short* __restrict__ WsT, unsigned short* __restrict__ WvT,
    unsigned short* __restrict__ Wu0T, unsigned short* __restrict__ Wu1T) {
    int idx = blockIdx.x * 256 + threadIdx.x;
    if (idx < 128 * 640) {
        int v = idx / 640, k = idx - v * 640;
        int a = k >> 6, u = k & 63;
        WsT[idx] = f2bf_bits(Wsk_s[(u * 10 + a) * 128 + v]);
        return;
    }
    int i2 = idx - 128 * 640;
    if (i2 < 64 * 640) {
        int v = i2 / 640, k = i2 - v * 640;
        int a = k >> 6, u = k & 63;
        WvT[i2] = f2bf_bits(Wsk_v[(u * 10 + a) * 64 + v]);
        return;
    }
    int i3 = i2 - 64 * 640;
    if (i3 < 4096) { Wu0T[i3] = f2bf_bits(Wu0[(i3 & 63) * 64 + (i3 >> 6)]); return; }
    int i4 = i3 - 4096;
    if (i4 < 4096) { Wu1T[i4] = f2bf_bits(Wu1[(i4 & 63) * 64 + (i4 >> 6)]); }
}

// ---------------- K_wprep2: FRAGMENT-MAJOR bf16 edge-MLP weights.
// WFG[f*512 + lane*8 + j]; f enumerates MFMA B-fragments in kernel read order:
//  f 0..3   : M1 tile nt=f          (K padded to 32; k = quad*8+j, real k<8)
//  f 4..11  : M2 (nt = (f-4)>>1, half = (f-4)&1; k = half*32+quad*8+j)
//  f 12..19 : M3 (same scheme)
//  f 20..51 : M4 (tt = (f-20)>>1 in 0..15, half; n = tt*16+lo)
__global__ __launch_bounds__(256) void k_wprep2(
    const float* __restrict__ M1, const float* __restrict__ M2,
    const float* __restrict__ M3, const float* __restrict__ M4,
    unsigned short* __restrict__ WFG) {
    int idx = blockIdx.x * 256 + threadIdx.x;
    if (idx >= 52 * 512) return;
    int f = idx >> 9, r = idx & 511;
    int lane = r >> 3, j = r & 7;
    int quad = lane >> 4, lo = lane & 15;
    float val;
    if (f < 4) {
        int n = f * 16 + lo, k = quad * 8 + j;
        val = (k < 8) ? M1[k * 64 + n] : 0.f;
    } else if (f < 12) {
        int g2 = f - 4, nt = g2 >> 1, half = g2 & 1;
        int n = nt * 16 + lo, k = half * 32 + quad * 8 + j;
        val = M2[k * 64 + n];
    } else if (f < 20) {
        int g3 = f - 12, nt = g3 >> 1, half = g3 & 1;
        int n = nt * 16 + lo, k = half * 32 + quad * 8 + j;
        val = M3[k * 64 + n];
    } else {
        int g4 = f - 20, tt = g4 >> 1, half = g4 & 1;
        int n = tt * 16 + lo, k = half * 32 + quad * 8 + j;
        val = M4[k * 256 + n];
    }
    WFG[idx] = f2bf_bits(val);
}

// ---------------- K_node: fused MFMA node-side einsums (16 nodes/block).
#define FEAT_STRIDE 72

__global__ __launch_bounds__(256) void k_node(
    const float* __restrict__ node_attrs, const float* __restrict__ node_feats,
    const unsigned short* __restrict__ WsT, const unsigned short* __restrict__ WvT,
    const unsigned short* __restrict__ Wu0T, const unsigned short* __restrict__ Wu1T,
    float* __restrict__ sc_s, float* __restrict__ sc_v,
    float* __restrict__ x0u, float* __restrict__ x1u) {
    __shared__ unsigned short feat[4 * 16 * FEAT_STRIDE];  // plane 0=x0, 1..3=x1_i
    __shared__ float attrs_l[16 * 12];
    __shared__ float x1st[16 * 64 * 4];                    // packed float4 staging

    int t = threadIdx.x;
    int nbase = blockIdx.x * 16;

    {
        int node = t >> 4, seg = t & 15;
        const float* src = node_feats + (long)(nbase + node) * 256 + seg * 16;
        #pragma unroll
        for (int f = 0; f < 16; f += 4) {
            float4 v4 = *(const float4*)(src + f);
            float vv[4] = {v4.x, v4.y, v4.z, v4.w};
            #pragma unroll
            for (int j = 0; j < 4; j++) {
                int fi = seg * 16 + f + j;
                unsigned short b = f2bf_bits(vv[j]);
                if (fi < 64) {
                    feat[(0 * 16 + node) * FEAT_STRIDE + fi] = b;
                } else {
                    int r = fi - 64;
                    int u = r / 3;
                    int i = r - u * 3;
                    feat[((1 + i) * 16 + node) * FEAT_STRIDE + u] = b;
                }
            }
        }
    }
    if (t < 160) {
        int node = t / 10, a = t - node * 10;
        attrs_l[node * 12 + a] = node_attrs[(long)(nbase + node) * 10 + a];
    }
    __syncthreads();

    int wv = t >> 6;
    int lane = t & 63;
    int lo = lane & 15;
    int quad = lane >> 4;
    const f32x4 zacc = {0.f, 0.f, 0.f, 0.f};

    float af[10];
    #pragma unroll
    for (int a = 0; a < 10; a++) af[a] = attrs_l[lo * 12 + a];
    bf16x8 ff0h0 = *(const bf16x8*)&feat[(0 * 16 + lo) * FEAT_STRIDE + 0 * 32 + quad * 8];
    bf16x8 ff0h1 = *(const bf16x8*)&feat[(0 * 16 + lo) * FEAT_STRIDE + 1 * 32 + quad * 8];
    bf16x8 ff1h0 = *(const bf16x8*)&feat[(1 * 16 + lo) * FEAT_STRIDE + 0 * 32 + quad * 8];
    bf16x8 ff1h1 = *(const bf16x8*)&feat[(1 * 16 + lo) * FEAT_STRIDE + 1 * 32 + quad * 8];
    bf16x8 ff2h0 = *(const bf16x8*)&feat[(2 * 16 + lo) * FEAT_STRIDE + 0 * 32 + quad * 8];
    bf16x8 ff2h1 = *(const bf16x8*)&feat[(2 * 16 + lo) * FEAT_STRIDE + 1 * 32 + quad * 8];
    bf16x8 ff3h0 = *(const bf16x8*)&feat[(3 * 16 + lo) * FEAT_STRIDE + 0 * 32 + quad * 8];
    bf16x8 ff3h1 = *(const bf16x8*)&feat[(3 * 16 + lo) * FEAT_STRIDE + 1 * 32 + quad * 8];

    #pragma unroll 1
    for (int q = 0; q < 9; q++) {
        int tau = wv + q * 4;
        int kind, vt, iidx = 0, plane;
        const unsigned short* brow;
        if (tau < 8)       { kind = 0; vt = tau;               plane = 0;        brow = WsT  + (size_t)(vt * 16 + lo) * 640; }
        else if (tau < 20) { kind = 1; iidx = (tau - 8) >> 2;  vt = (tau - 8) & 3;  plane = 1 + iidx; brow = WvT  + (size_t)(vt * 16 + lo) * 640; }
        else if (tau < 24) { kind = 2; vt = tau - 20;          plane = 0;        brow = Wu0T + (size_t)(vt * 16 + lo) * 64; }
        else               { kind = 3; iidx = (tau - 24) >> 2; vt = (tau - 24) & 3; plane = 1 + iidx; brow = Wu1T + (size_t)(vt * 16 + lo) * 64; }

        bf16x8 fa0, fa1;
        if (plane == 0)      { fa0 = ff0h0; fa1 = ff0h1; }
        else if (plane == 1) { fa0 = ff1h0; fa1 = ff1h1; }
        else if (plane == 2) { fa0 = ff2h0; fa1 = ff2h1; }
        else                 { fa0 = ff3h0; fa1 = ff3h1; }

        f32x4 acc = zacc;
        if (kind <= 1) {
            #pragma unroll
            for (int kc = 0; kc < 20; kc++) {
                bf16x8 b = *(const bf16x8*)(brow + kc * 32 + quad * 8);
                bf16x8 a = scale8((kc & 1) ? fa1 : fa0, af[kc >> 1]);
                acc = __builtin_amdgcn_mfma_f32_16x16x32_bf16(a, b, acc, 0, 0, 0);
            }
        } else {
            bf16x8 b0 = *(const bf16x8*)(brow + quad * 8);
            bf16x8 b1 = *(const bf16x8*)(brow + 32 + quad * 8);
            acc = __builtin_amdgcn_mfma_f32_16x16x32_bf16(fa0, b0, acc, 0, 0, 0);
            acc = __builtin_amdgcn_mfma_f32_16x16x32_bf16(fa1, b1, acc, 0, 0, 0);
        }

        #pragma unroll
        for (int r = 0; r < 4; r++) {
            int nrow = nbase + quad * 4 + r;
            float cv = acc[r];
            if (kind == 0)      sc_s[(long)nrow * 128 + vt * 16 + lo] = cv * SK_NORM;
            else if (kind == 1) sc_v[(long)nrow * 192 + iidx * 64 + vt * 16 + lo] = cv * SK_NORM;
            else if (kind == 2) x0u[(long)nrow * 64 + vt * 16 + lo] = cv * UP_NORM;
            else                x1st[((quad * 4 + r) * 64 + vt * 16 + lo) * 4 + iidx] = cv * UP_NORM;
        }
    }
    __syncthreads();
    #pragma unroll
    for (int j = 0; j < 4; j++) {
        int idx = t + j * 256;
        int node = idx >> 6, v = idx & 63;
        ((float4*)x1u)[(long)(nbase + node) * 64 + v] = *(const float4*)&x1st[idx * 4];
    }
}

// ---------------- K3: CSR build by receiver (epk = packed {sender, edge})
__global__ __launch_bounds__(256) void k_hist(const int* __restrict__ rcv, int* __restrict__ counts) {
    int e = blockIdx.x * 256 + threadIdx.x;
    if (e < NE) atomicAdd(&counts[rcv[e]], 1);
}

__global__ __launch_bounds__(1024) void k_scan(const int* __restrict__ counts, int* __restrict__ offsets) {
    __shared__ int partial[1024];
    int t = threadIdx.x;
    const int CHUNK = (NN + 1023) / 1024;   // 10
    int base = t * CHUNK;
    int s = 0;
    for (int i = 0; i < CHUNK; i++) if (base + i < NN) s += counts[base + i];
    partial[t] = s;
    __syncthreads();
    for (int d = 1; d < 1024; d *= 2) {
        int v = (t >= d) ? partial[t - d] : 0;
        __syncthreads();
        partial[t] += v;
        __syncthreads();
    }
    int excl = (t == 0) ? 0 : partial[t - 1];
    for (int i = 0; i < CHUNK; i++) {
        if (base + i < NN) { offsets[base + i] = excl; excl += counts[base + i]; }
    }
    if (t == 1023) offsets[NN] = partial[1023];
}

__global__ __launch_bounds__(256) void k_fill(const int* __restrict__ rcv, const int* __restrict__ snd,
                                              const int* __restrict__ offsets,
                                              int* __restrict__ cursor, int2* __restrict__ epk) {
    int e = blockIdx.x * 256 + threadIdx.x;
    if (e < NE) {
        int r = rcv[e];
        int pos = atomicAdd(&cursor[r], 1);
        epk[offsets[r] + pos] = make_int2(snd[e], e);
    }
}

// ---------------- K_eprep: CSR-ordered edge streams: sndp[j], earp[j], eaip[j], efp[j]
__global__ __launch_bounds__(256) void k_eprep(const int2* __restrict__ epk,
                                               const float4* __restrict__ ear, const float4* __restrict__ eai,
                                               const float4* __restrict__ ef,
                                               int* __restrict__ sndp,
                                               float4* __restrict__ earp, float4* __restrict__ eaip,
                                               float4* __restrict__ efp) {
    int j = blockIdx.x * 256 + threadIdx.x;
    if (j >= NE) return;
    int2 se = epk[j];
    sndp[j] = se.x;
    earp[j] = ear[se.y];
    eaip[j] = eai[se.y];
    efp[(long)j * 2]     = ef[(long)se.y * 2];
    efp[(long)j * 2 + 1] = ef[(long)se.y * 2 + 1];
}

// ---------------- K2: edge MLP via MFMA, CSR-slot order -> twp (bf16, NE x 256)
// Weights staged ONCE per block from fragment-major WFG (pure sequential 16B copy,
// no transpose/cvt). All B reads: lane i at base+i*16 => ZERO bank conflicts.
// obuf aliases hid (dead after layer-4 A-frag regs; same-wave DS ops are in-order).
// EPB=128 edges/block (2 groups of 16/wave) amortizes staging.
#define HID_STRIDE 72
#define OB_STRIDE  40
#define EPB 128

__global__ __launch_bounds__(256) void k_edge_mlp(
    const float4* __restrict__ efp, const unsigned short* __restrict__ WFG,
    __hip_bfloat16* __restrict__ twp) {
    __shared__ unsigned short wfrag[52 * 512];          // 53248 B
    __shared__ unsigned short hid[4][16 * HID_STRIDE];  //  9216 B

    int t = threadIdx.x;
    // stage fragment-major weights: 3328 x 16B sequential copy
    for (int i = t; i < 52 * 512 / 8; i += 256)
        ((float4*)wfrag)[i] = ((const float4*)WFG)[i];
    __syncthreads();

    int wv = t >> 6;
    int lane = t & 63;
    int lo = lane & 15;
    int quad = lane >> 4;
    int lbase = lane * 8;
    unsigned short* myhid = hid[wv];
    unsigned short* myob  = hid[wv];    // alias; safe per-wave in-order DS
    const f32x4 zacc = {0.f, 0.f, 0.f, 0.f};

    #pragma unroll 1
    for (int g = 0; g < EPB / 64; g++) {
        int jbase = blockIdx.x * EPB + g * 64 + wv * 16;

        // ---- layer 1: [16x8] @ [8x64] (K padded to 32), silu ----
        bf16x8 a1 = {0, 0, 0, 0, 0, 0, 0, 0};
        if (quad == 0) {
            float4 f0 = efp[(long)(jbase + lo) * 2];
            float4 f1 = efp[(long)(jbase + lo) * 2 + 1];
            union { unsigned short us[8]; bf16x8 v; } pk;
            pk.us[0] = f2bf_bits(f0.x * M1_NORM); pk.us[1] = f2bf_bits(f0.y * M1_NORM);
            pk.us[2] = f2bf_bits(f0.z * M1_NORM); pk.us[3] = f2bf_bits(f0.w * M1_NORM);
            pk.us[4] = f2bf_bits(f1.x * M1_NORM); pk.us[5] = f2bf_bits(f1.y * M1_NORM);
            pk.us[6] = f2bf_bits(f1.z * M1_NORM); pk.us[7] = f2bf_bits(f1.w * M1_NORM);
            a1 = pk.v;
        }
        {
            f32x4 acc[4];
            #pragma unroll
            for (int nt = 0; nt < 4; nt++) {
                bf16x8 b = *(const bf16x8*)&wfrag[nt * 512 + lbase];
                acc[nt] = __builtin_amdgcn_mfma_f32_16x16x32_bf16(a1, b, zacc, 0, 0, 0);
            }
            #pragma unroll
            for (int nt = 0; nt < 4; nt++)
                #pragma unroll
                for (int r = 0; r < 4; r++)
                    myhid[(quad * 4 + r) * HID_STRIDE + nt * 16 + lo] = f2bf_bits(siluf(acc[nt][r]));
        }

        // ---- layers 2,3: [16x64] @ [64x64] /8, silu ----
        #pragma unroll
        for (int L = 0; L < 2; L++) {
            int fb = 4 + L * 8;
            bf16x8 a0 = *(const bf16x8*)&myhid[lo * HID_STRIDE + quad * 8];
            bf16x8 a1v = *(const bf16x8*)&myhid[lo * HID_STRIDE + 32 + quad * 8];
            f32x4 acc[4];
            #pragma unroll
            for (int nt = 0; nt < 4; nt++) {
                bf16x8 b0 = *(const bf16x8*)&wfrag[(fb + nt * 2) * 512 + lbase];
                bf16x8 b1 = *(const bf16x8*)&wfrag[(fb + nt * 2 + 1) * 512 + lbase];
                acc[nt] = __builtin_amdgcn_mfma_f32_16x16x32_bf16(a0, b0, zacc, 0, 0, 0);
                acc[nt] = __builtin_amdgcn_mfma_f32_16x16x32_bf16(a1v, b1, acc[nt], 0, 0, 0);
            }
            #pragma unroll
            for (int nt = 0; nt < 4; nt++)
                #pragma unroll
                for (int r = 0; r < 4; r++)
                    myhid[(quad * 4 + r) * HID_STRIDE + nt * 16 + lo] = f2bf_bits(siluf(acc[nt][r] * 0.125f));
        }

        // ---- layer 4: [16x64] @ [64x256] /8, interleaved (A,B)/(C,D) pair output ----
        {
            bf16x8 a0 = *(const bf16x8*)&myhid[lo * HID_STRIDE + quad * 8];
            bf16x8 a1v = *(const bf16x8*)&myhid[lo * HID_STRIDE + 32 + quad * 8];
            int sedge = lane >> 2, sch = lane & 3;
            #pragma unroll 1
            for (int rd = 0; rd < 8; rd++) {
                f32x4 acc2[2];
                #pragma unroll
                for (int p = 0; p < 2; p++) {
                    int tt = (rd < 4) ? (p * 4 + rd) : (8 + p * 4 + (rd - 4));
                    bf16x8 b0 = *(const bf16x8*)&wfrag[(20 + tt * 2) * 512 + lbase];
                    bf16x8 b1 = *(const bf16x8*)&wfrag[(20 + tt * 2 + 1) * 512 + lbase];
                    acc2[p] = __builtin_amdgcn_mfma_f32_16x16x32_bf16(a0, b0, zacc, 0, 0, 0);
                    acc2[p] = __builtin_amdgcn_mfma_f32_16x16x32_bf16(a1v, b1, acc2[p], 0, 0, 0);
                }
                #pragma unroll
                for (int p = 0; p < 2; p++)
                    #pragma unroll
                    for (int r = 0; r < 4; r++)
                        myob[(quad * 4 + r) * OB_STRIDE + 2 * lo + p] = f2bf_bits(acc2[p][r] * 0.125f);
                bf16x8 vv = *(const bf16x8*)&myob[sedge * OB_STRIDE + sch * 8];
                *(bf16x8*)(twp + (long)(jbase + sedge) * 256 + rd * 32 + sch * 8) = vv;
            }
        }
    }
}

// ---------------- K4: conv_tp + segment sum -> msg (bf16, NN x 1024)
#define CB 8
__global__ __launch_bounds__(256) void k_conv(
    const int* __restrict__ offsets, const int* __restrict__ sndp,
    const float4* __restrict__ earp, const float4* __restrict__ eaip,
    const float* __restrict__ x0u, const float* __restrict__ x1u,
    const __hip_bfloat16* __restrict__ twp,
    unsigned short* __restrict__ msgbuf) {
    int n = blockIdx.x;
    int t = threadIdx.x;
    int u = t & 127;
    int ri = t >> 7;
    int beg = offsets[n], end = offsets[n + 1];
    const float4* ea4 = ri ? eaip : earp;
    float a0 = 0.f, a1 = 0.f, a2 = 0.f, a3 = 0.f;
    if (u < 64) {
        const int tsel = 2 * u;
        for (int jb = beg; jb < end; jb += CB) {
            unsigned int twd[CB]; float x0v[CB]; float4 y[CB];
            #pragma unroll
            for (int p = 0; p < CB; p++) {
                int j = jb + p;
                int jc = (j < end) ? j : (end - 1);
                int s = sndp[jc];
                y[p] = ea4[jc];
                x0v[p] = x0u[(long)s * 64 + u];
                twd[p] = (j < end) ? *(const unsigned int*)(twp + (long)jc * 256 + tsel) : 0u;
            }
            #pragma unroll
            for (int p = 0; p < CB; p++) {
                float wA = bflo(twd[p]), wB = bfhi(twd[p]);
                a0 += x0v[p] * y[p].x * wA;
                float xb = x0v[p] * wB;
                a1 += xb * y[p].y; a2 += xb * y[p].z; a3 += xb * y[p].w;
            }
        }
    } else {
        int uu = u - 64;
        const int tsel = 128 + 2 * uu;
        for (int jb = beg; jb < end; jb += CB) {
            unsigned int twd[CB]; float4 x1v[CB]; float4 y[CB];
            #pragma unroll
            for (int p = 0; p < CB; p++) {
                int j = jb + p;
                int jc = (j < end) ? j : (end - 1);
                int s = sndp[jc];
                y[p] = ea4[jc];
                x1v[p] = ((const float4*)x1u)[(long)s * 64 + uu];
                twd[p] = (j < end) ? *(const unsigned int*)(twp + (long)jc * 256 + tsel) : 0u;
            }
            #pragma unroll
            for (int p = 0; p < CB; p++) {
                float wC = bflo(twd[p]), wD = bfhi(twd[p]);
                a0 += (x1v[p].x * y[p].y + x1v[p].y * y[p].z + x1v[p].z * y[p].w) * INV3 * wD;
                float yc = y[p].x * wC;
                a1 += x1v[p].x * yc; a2 += x1v[p].y * yc; a3 += x1v[p].z * yc;
            }
        }
    }
    unsigned short* mb = msgbuf + (long)n * 1024;
    mb[ri * 128 + u] = f2bf_bits(a0);
    int vb = 256 + ri * 384 + u;
    mb[vb + 0]   = f2bf_bits(a1);
    mb[vb + 128] = f2bf_bits(a2);
    mb[vb + 256] = f2bf_bits(a3);
}

// ---------------- K5: MFMA lin + skip + gate + output.
#define WL_STRIDE 136   // 128 k + 8 pad (16B-aligned rows)
#define SV_STRIDE 129   // sval row pad
#define VV_STRIDE 65    // vval row pad

__global__ __launch_bounds__(256) void k_lin(
    const unsigned short* __restrict__ msgbuf,
    const float* __restrict__ sc_s, const float* __restrict__ sc_v,
    const float* __restrict__ W_lin_s, const float* __restrict__ W_lin_v,
    float* __restrict__ out) {
    __shared__ unsigned short wst[128 * WL_STRIDE];
    __shared__ unsigned short wvt[64 * WL_STRIDE];
    __shared__ float sval[2 * 16 * SV_STRIDE];
    __shared__ float vval[2 * 3 * 16 * VV_STRIDE];

    int t = threadIdx.x;
    for (int idx = t; idx < 128 * 128; idx += 256) {
        int k = idx >> 7, v = idx & 127;
        wst[v * WL_STRIDE + k] = f2bf_bits(W_lin_s[idx]);
    }
    for (int idx = t; idx < 128 * 64; idx += 256) {
        int k = idx >> 6, v = idx & 63;
        wvt[v * WL_STRIDE + k] = f2bf_bits(W_lin_v[idx]);
    }
    __syncthreads();

    int wv = t >> 6;
    int lane = t & 63;
    int lo = lane & 15;
    int quad = lane >> 4;
    const f32x4 zacc = {0.f, 0.f, 0.f, 0.f};

    for (int g = blockIdx.x; g < NN / 16; g += gridDim.x) {
        long nbase = (long)g * 16;
        const unsigned short* arow = msgbuf + (nbase + lo) * 1024;

        #pragma unroll 1
        for (int q = 0; q < 10; q++) {
            int tau = wv + q * 4;
            int aoff, cidx, cstride;
            const unsigned short* bptr;
            float* cbuf;
            if (tau < 16) {
                int ri = tau >> 3, vt = tau & 7;
                aoff = ri * 128;
                bptr = &wst[(vt * 16 + lo) * WL_STRIDE];
                cbuf = sval;
                cidx = (ri * 16) * SV_STRIDE + vt * 16 + lo;
                cstride = SV_STRIDE;
            } else {
                int tp = tau - 16;
                int ri = tp / 12, rem = tp % 12;
                int i = rem >> 2, vt = rem & 3;
                aoff = 256 + ri * 384 + i * 128;
                bptr = &wvt[(vt * 16 + lo) * WL_STRIDE];
                cbuf = vval;
                cidx = ((ri * 3 + i) * 16) * VV_STRIDE + vt * 16 + lo;
                cstride = VV_STRIDE;
            }
            f32x4 acc = zacc;
            #pragma unroll
            for (int ks = 0; ks < 4; ks++) {
                bf16x8 a = *(const bf16x8*)(arow + aoff + ks * 32 + quad * 8);
                bf16x8 b = *(const bf16x8*)(bptr + ks * 32 + quad * 8);
                acc = __builtin_amdgcn_mfma_f32_16x16x32_bf16(a, b, acc, 0, 0, 0);
            }
            #pragma unroll
            for (int r = 0; r < 4; r++)
                cbuf[cidx + (quad * 4 + r) * cstride] = acc[r] * LIN_NORM;
        }
        __syncthreads();

        #pragma unroll 1
        for (int j = 0; j < 16; j++) {
            int c = t;
            long gn = nbase + j;
            float re, im;
            if (c < 64) {
                float sr = sval[(0 * 16 + j) * SV_STRIDE + c] + sc_s[gn * 128 + c];
                float si = sval[(1 * 16 + j) * SV_STRIDE + c];
                re = siluf(sr); im = siluf(si);
            } else {
                int rem = c - 64;
                int v = rem / 3;
                int i = rem - v * 3;
                float gr = siluf(sval[(0 * 16 + j) * SV_STRIDE + 64 + v] + sc_s[gn * 128 + 64 + v]);
                float gi = siluf(sval[(1 * 16 + j) * SV_STRIDE + 64 + v]);
                float lr = vval[((0 * 3 + i) * 16 + j) * VV_STRIDE + v] + sc_v[gn * 192 + i * 64 + v];
                float li = vval[((1 * 3 + i) * 16 + j) * VV_STRIDE + v];
                re = lr * gr; im = li * gi;
            }
            ((float2*)out)[gn * 256 + c] = make_float2(re, im);
        }
        __syncthreads();
    }
}

extern "C" void kernel_launch(void* const* d_in, const int* in_sizes, int n_in,
                              void* d_out, int out_size, void* d_ws, size_t ws_size,
                              hipStream_t stream) {
    const float* node_attrs = (const float*)d_in[0];
    const float* node_feats = (const float*)d_in[1];
    const float* ear        = (const float*)d_in[2];
    const float* eai        = (const float*)d_in[3];
    const float* edge_feats = (const float*)d_in[4];
    const float* W_up0      = (const float*)d_in[5];
    const float* W_up1      = (const float*)d_in[6];
    const float* M1         = (const float*)d_in[7];
    const float* M2         = (const float*)d_in[8];
    const float* M3         = (const float*)d_in[9];
    const float* M4         = (const float*)d_in[10];
    const float* W_lin_s    = (const float*)d_in[11];
    const float* W_lin_v    = (const float*)d_in[12];
    const float* W_sk_s     = (const float*)d_in[13];
    const float* W_sk_v     = (const float*)d_in[14];
    const int*   ei         = (const int*)d_in[15];

    char* ws = (char*)d_ws;
    size_t o_x0u = 0;
    size_t o_x1u = o_x0u + (size_t)NN * 64 * 4;
    size_t o_scs = o_x1u + (size_t)NN * 256 * 4;      // x1u4: [n][64][4]
    size_t o_scv = o_scs + (size_t)NN * 128 * 4;
    size_t o_tw  = o_scv + (size_t)NN * 192 * 4;
    size_t o_cnt = o_tw  + (size_t)NE * 256 * 2;
    size_t o_cur = o_cnt + (size_t)NN * 4;
    size_t o_ofs = o_cur + (size_t)NN * 4;
    size_t o_epk = o_ofs + (size_t)(NN + 1) * 4 + 60;   // pad to 16B
    size_t o_snd = o_epk + (size_t)NE * 8;
    size_t o_rcv = o_snd + (size_t)NE * 4;
    size_t o_flg = o_rcv + (size_t)NE * 4;
    size_t o_msg = o_flg + 64;
    size_t o_wst = o_msg + (size_t)NN * 1024 * 2;
    size_t o_wvt = o_wst + (size_t)128 * 640 * 2;
    size_t o_wu0 = o_wvt + (size_t)64 * 640 * 2;
    size_t o_wu1 = o_wu0 + (size_t)4096 * 2;
    size_t o_snp = o_wu1 + (size_t)4096 * 2;            // sndp (CSR order)
    size_t o_erp = o_snp + (size_t)NE * 4;
    size_t o_eip = o_erp + (size_t)NE * 16;
    size_t o_efp = o_eip + (size_t)NE * 16;             // efp (CSR-ordered edge_feats)
    size_t o_wfg = o_efp + (size_t)NE * 32;             // fragment-major MLP weights
    float* x0u = (float*)(ws + o_x0u);
    float* x1u = (float*)(ws + o_x1u);
    float* sc_s = (float*)(ws + o_scs);
    float* sc_v = (float*)(ws + o_scv);
    __hip_bfloat16* twp = (__hip_bfloat16*)(ws + o_tw);
    int* counts  = (int*)(ws + o_cnt);
    int* cursor  = (int*)(ws + o_cur);
    int* offsets = (int*)(ws + o_ofs);
    int2* epk    = (int2*)(ws + o_epk);
    int* snd     = (int*)(ws + o_snd);
    int* rcv     = (int*)(ws + o_rcv);
    int* flag    = (int*)(ws + o_flg);
    unsigned short* msgbuf = (unsigned short*)(ws + o_msg);
    unsigned short* WsT  = (unsigned short*)(ws + o_wst);
    unsigned short* WvT  = (unsigned short*)(ws + o_wvt);
    unsigned short* Wu0T = (unsigned short*)(ws + o_wu0);
    unsigned short* Wu1T = (unsigned short*)(ws + o_wu1);
    int*    sndp = (int*)(ws + o_snp);
    float4* earp = (float4*)(ws + o_erp);
    float4* eaip = (float4*)(ws + o_eip);
    float4* efp  = (float4*)(ws + o_efp);
    unsigned short* WFG = (unsigned short*)(ws + o_wfg);

    hipMemsetAsync(ws + o_cnt, 0, (size_t)NN * 8, stream);

    dim3 b256(256), b1024(1024);
    k_detect<<<dim3(1), b256, 0, stream>>>(ei, flag);
    k_cvt   <<<dim3((NE + 255) / 256), b256, 0, stream>>>(ei, flag, snd, rcv);
    k_hist<<<dim3((NE + 255) / 256), b256, 0, stream>>>(rcv, counts);
    k_scan<<<dim3(1), b1024, 0, stream>>>(counts, offsets);
    k_fill<<<dim3((NE + 255) / 256), b256, 0, stream>>>(rcv, snd, offsets, cursor, epk);
    k_eprep<<<dim3((NE + 255) / 256), b256, 0, stream>>>(epk, (const float4*)ear, (const float4*)eai,
                                                         (const float4*)edge_feats,
                                                         sndp, earp, eaip, efp);
    k_wprep <<<dim3(512), b256, 0, stream>>>(W_sk_s, W_sk_v, W_up0, W_up1, WsT, WvT, Wu0T, Wu1T);
    k_wprep2<<<dim3(104), b256, 0, stream>>>(M1, M2, M3, M4, WFG);
    k_node  <<<dim3(NN / 16), b256, 0, stream>>>(node_attrs, node_feats, WsT, WvT, Wu0T, Wu1T,
                                                 sc_s, sc_v, x0u, x1u);
    k_edge_mlp<<<dim3(NE / EPB), b256, 0, stream>>>(efp, WFG, twp);
    k_conv<<<dim3(NN), b256, 0, stream>>>(offsets, sndp, earp, eaip, x0u, x1u, twp, msgbuf);
    k_lin <<<dim3(224), b256, 0, stream>>>(msgbuf, sc_s, sc_v, W_lin_s, W_lin_v, (float*)d_out);
}